// Round 12
// baseline (162.646 us; speedup 1.0000x reference)
//
#include <hip/hip_runtime.h>
#include <hip/hip_bf16.h>
#include <math.h>

// B=256, D=256, H=8, FF=1024, M=2048
#define SCALE_F 0.17677669529663687f

typedef __attribute__((ext_vector_type(8))) short short8;
typedef __attribute__((ext_vector_type(4))) short short4v;
typedef __attribute__((ext_vector_type(4))) float f32x4;

__device__ inline short tobf(float x) {
    union { __hip_bfloat16 b; short s; } u;
    u.b = __float2bfloat16(x);
    return u.s;
}
__device__ inline float frombf(short s) {
    return __uint_as_float(((unsigned)(unsigned short)s) << 16);
}

__device__ __forceinline__ short8 cv8(const float* __restrict__ p) {
    float4 a = *(const float4*)p, b = *(const float4*)(p + 4);
    short8 o = {tobf(a.x), tobf(a.y), tobf(a.z), tobf(a.w),
                tobf(b.x), tobf(b.y), tobf(b.z), tobf(b.w)};
    return o;
}

// ---------- staged-convert GEMM 64x64 ----------
__device__ __forceinline__ void gemm_cv(short* lds,
    const float* __restrict__ A, int lda,
    const float* __restrict__ B, int ldb,
    short* Cb, int ldc, const float* bias, int bx, int by)
{
    short* Al = lds;
    short* Bl = lds + 2560;
    int t = threadIdx.x, w = t >> 6, l = t & 63;
    int r0 = by * 64, c0 = bx * 64;
    int srow = t >> 2, scol = (t & 3) * 8;
    f32x4 acc[4] = {{0.f,0.f,0.f,0.f},{0.f,0.f,0.f,0.f},{0.f,0.f,0.f,0.f},{0.f,0.f,0.f,0.f}};
    for (int kk = 0; kk < 256; kk += 32) {
        *(short8*)&Al[srow * 40 + scol] = cv8(A + (long long)(r0 + srow) * lda + kk + scol);
        *(short8*)&Bl[srow * 40 + scol] = cv8(B + (long long)(c0 + srow) * ldb + kk + scol);
        __syncthreads();
        short8 af = *(const short8*)&Al[(w * 16 + (l & 15)) * 40 + (l >> 4) * 8];
        #pragma unroll
        for (int j = 0; j < 4; j++) {
            short8 bf = *(const short8*)&Bl[(j * 16 + (l & 15)) * 40 + (l >> 4) * 8];
            acc[j] = __builtin_amdgcn_mfma_f32_16x16x32_bf16(af, bf, acc[j], 0, 0, 0);
        }
        __syncthreads();
    }
    int lc = l & 15, lr = (l >> 4) * 4;
    #pragma unroll
    for (int j = 0; j < 4; j++) {
        int col = c0 + j * 16 + lc;
        float bv = bias[col];
        #pragma unroll
        for (int r = 0; r < 4; r++) {
            int row = r0 + w * 16 + lr + r;
            Cb[(long long)row * ldc + col] = tobf(acc[j][r] + bv);
        }
    }
}

// ---------- staged-convert GEMM 64x128 (f32 out or dual k/vt) ----------
__device__ __forceinline__ void gemm_cv128(short* lds,
    const float* __restrict__ A, int lda,
    const float* __restrict__ B, int ldb,
    float* Cf, int ldcF, short* Ck, short* Cvt, const float* bias,
    int bx, int by)
{
    short* Al = lds;
    short* Bl = lds + 2560;
    int t = threadIdx.x, w = t >> 6, l = t & 63;
    int r0 = by * 64, c0 = bx * 128;
    int srow = t >> 2, scol = (t & 3) * 8;
    f32x4 acc[8] = {{0.f,0.f,0.f,0.f},{0.f,0.f,0.f,0.f},{0.f,0.f,0.f,0.f},{0.f,0.f,0.f,0.f},
                    {0.f,0.f,0.f,0.f},{0.f,0.f,0.f,0.f},{0.f,0.f,0.f,0.f},{0.f,0.f,0.f,0.f}};
    for (int kk = 0; kk < 256; kk += 32) {
        *(short8*)&Al[srow * 40 + scol] = cv8(A + (long long)(r0 + srow) * lda + kk + scol);
        #pragma unroll
        for (int s = 0; s < 2; s++) {
            int seg = t + s * 256;
            int brow = seg >> 2, boff = (seg & 3) * 8;
            *(short8*)&Bl[brow * 40 + boff] = cv8(B + (long long)(c0 + brow) * ldb + kk + boff);
        }
        __syncthreads();
        short8 af = *(const short8*)&Al[(w * 16 + (l & 15)) * 40 + (l >> 4) * 8];
        #pragma unroll
        for (int j = 0; j < 8; j++) {
            short8 bf = *(const short8*)&Bl[(j * 16 + (l & 15)) * 40 + (l >> 4) * 8];
            acc[j] = __builtin_amdgcn_mfma_f32_16x16x32_bf16(af, bf, acc[j], 0, 0, 0);
        }
        __syncthreads();
    }
    int lc = l & 15, lr = (l >> 4) * 4;
    #pragma unroll
    for (int j = 0; j < 8; j++) {
        int col = c0 + j * 16 + lc;
        float bv = bias ? bias[col] : 0.f;
        #pragma unroll
        for (int r = 0; r < 4; r++) {
            int row = r0 + w * 16 + lr + r;
            float v = acc[j][r] + bv;
            if (Cf) Cf[(long long)row * ldcF + col] = v;
            else if (col < 256) Ck[(long long)row * 256 + col] = tobf(v);
            else                Cvt[(long long)(col - 256) * 2048 + row] = tobf(v);
        }
    }
}

// ---------- 1. projections + conversions + norms (420 blocks) ----------
__global__ __launch_bounds__(256) void proj_k(
    const float* __restrict__ src, const float* __restrict__ memory,
    const float* __restrict__ ipw, const float* __restrict__ ipb,
    const float* __restrict__ out_w, const float* __restrict__ w1, const float* __restrict__ w2,
    float* __restrict__ simdot, short* __restrict__ qkv_bf,
    short* __restrict__ k_bf, short* __restrict__ vt_bf,
    short* __restrict__ outw_bf, short* __restrict__ w1_bf, short* __restrict__ w2_bf,
    float* __restrict__ nx, float* __restrict__ nm, float* __restrict__ nm2)
{
    __shared__ short lds[7680];
    int bid = blockIdx.x, t = threadIdx.x, w = t >> 6, l = t & 63;
    if (bid < 64) {
        gemm_cv128(lds, src, 256, memory, 256,
                   simdot, 2048, nullptr, nullptr, nullptr, bid & 15, bid >> 4);
    } else if (bid < 192) {
        int r = bid - 64;
        gemm_cv128(lds, memory, 256, ipw + 65536, 256,
                   nullptr, 0, k_bf, vt_bf, ipb + 256, r & 3, r >> 2);
    } else if (bid < 240) {
        int r = bid - 192;
        gemm_cv(lds, src, 256, ipw, 256, qkv_bf, 768, ipb, r % 12, r / 12);
    } else if (bid < 276) {
        int nb = bid - 240;
        #pragma unroll
        for (int i = 0; i < 16; i++) {
            int r = nb * 64 + i * 4 + w;
            bool issrc = r < 256;
            int rr = issrc ? r : r - 256;
            const float* rowp = issrc ? src + (long long)rr * 256 : memory + (long long)rr * 256;
            float4 x = *(const float4*)(rowp + l * 4);
            float ss = x.x * x.x + x.y * x.y + x.z * x.z + x.w * x.w;
            #pragma unroll
            for (int m = 32; m; m >>= 1) ss += __shfl_xor(ss, m, 64);
            if (l == 0) {
                if (issrc) nx[rr] = fmaxf(sqrtf(ss), 1e-8f);
                else { nm[rr] = fmaxf(sqrtf(ss), 1e-8f); nm2[rr] = ss; }
            }
        }
    } else {
        long long base = (long long)(bid - 276) * 4096 + t * 8;
        #pragma unroll
        for (int rep = 0; rep < 2; rep++) {
            long long e = base + rep * 2048;
            const float* sp; short* dp; long long off;
            if (e < 65536)       { sp = out_w; dp = outw_bf; off = e; }
            else if (e < 327680) { sp = w1;    dp = w1_bf;   off = e - 65536; }
            else                 { sp = w2;    dp = w2_bf;   off = e - 327680; }
            *(short8*)&dp[off] = cv8(sp + off);
        }
    }
}

// ---------- 2. flash attention (no-max softmax: logits bounded ~|0.6|) || surprise ----------
__global__ __launch_bounds__(256) void flash_sur_k(
    const short* __restrict__ qkv_bf, const short* __restrict__ k_bf,
    const short* __restrict__ vt_bf,
    float* __restrict__ pvpart, float* __restrict__ lpart,
    const float* __restrict__ simdot, const float* __restrict__ nx,
    const float* __restrict__ nm, const float* __restrict__ nm2, float* __restrict__ sur)
{
    __shared__ __align__(16) short smem[22016];   // Kl [128][40] | Pl [64][264]
    int bid = blockIdx.x, t = threadIdx.x;
    if (bid >= 256) {           // surprise
        float* red = (float*)smem;
        int b = bid - 256;
        float tot = 0.f;
        for (int m = t; m < 2048; m += 256) tot += nm2[m];
        red[t] = tot; __syncthreads();
        for (int s = 128; s; s >>= 1) { if (t < s) red[t] += red[t + s]; __syncthreads(); }
        float total = red[0];
        __syncthreads();
        float invx = 1.f / nx[b];
        float mx = -1e30f;
        for (int m = t; m < 2048; m += 256) {
            float d = simdot[(long long)b * 2048 + m];
            mx = fmaxf(mx, d * invx / nm[m]);
        }
        red[t] = mx; __syncthreads();
        for (int s = 128; s; s >>= 1) { if (t < s) red[t] = fmaxf(red[t], red[t + s]); __syncthreads(); }
        if (t == 0) sur[b] = (total == 0.f) ? 1.f : 1.f - red[0];
        return;
    }
    int ms = bid & 7, h = (bid >> 3) & 7, qt = bid >> 6;
    int q0 = qt * 64, m0 = ms * 256;
    int S = bid & 63;
    int w = t >> 6, l = t & 63;
    short* Kl = smem;
    short* Pl = smem + 5120;
    short8 af = *(const short8*)(qkv_bf + (q0 + w * 16 + (l & 15)) * 768 + h * 32 + (l >> 4) * 8);
    f32x4 accL[16];
    #pragma unroll
    for (int j = 0; j < 16; j++) accL[j] = f32x4{0.f, 0.f, 0.f, 0.f};
    #pragma unroll
    for (int half = 0; half < 2; half++) {
        #pragma unroll
        for (int s = 0; s < 2; s++) {
            int seg = t + s * 256; int row = seg >> 2, off = (seg & 3) * 8;
            *(short8*)&Kl[row * 40 + off] =
                *(const short8*)(k_bf + (long long)(m0 + half * 128 + row) * 256 + h * 32 + off);
        }
        __syncthreads();
        #pragma unroll
        for (int j = 0; j < 8; j++) {
            short8 bf = *(const short8*)&Kl[(j * 16 + (l & 15)) * 40 + (l >> 4) * 8];
            accL[half * 8 + j] = __builtin_amdgcn_mfma_f32_16x16x32_bf16(af, bf, accL[half * 8 + j], 0, 0, 0);
        }
        __syncthreads();
    }
    int r4 = (l >> 4) * 4;
    // exp directly (no max subtraction; logits bounded)
    #pragma unroll
    for (int j = 0; j < 16; j++)
        #pragma unroll
        for (int r = 0; r < 4; r++)
            accL[j][r] = __expf(accL[j][r] * SCALE_F);
    float lsum[4];
    #pragma unroll
    for (int r = 0; r < 4; r++) {
        float ls = 0.f;
        #pragma unroll
        for (int j = 0; j < 16; j++) ls += accL[j][r];
        #pragma unroll
        for (int msk = 1; msk < 16; msk <<= 1) ls += __shfl_xor(ls, msk, 64);
        lsum[r] = ls;
    }
    if ((l & 15) == 0) {
        #pragma unroll
        for (int r = 0; r < 4; r++)
            lpart[S * 256 + q0 + w * 16 + r4 + r] = lsum[r];
    }
    #pragma unroll
    for (int j = 0; j < 16; j++)
        #pragma unroll
        for (int r = 0; r < 4; r++)
            Pl[(w * 16 + r4 + r) * 264 + j * 16 + (l & 15)] = tobf(accL[j][r]);
    __syncthreads();
    f32x4 accP[2] = {{0.f,0.f,0.f,0.f},{0.f,0.f,0.f,0.f}};
    #pragma unroll
    for (int ks = 0; ks < 8; ks++) {
        short8 pa = *(const short8*)&Pl[(w * 16 + (l & 15)) * 264 + ks * 32 + (l >> 4) * 8];
        #pragma unroll
        for (int df = 0; df < 2; df++) {
            short8 vb = *(const short8*)(vt_bf + (long long)(h * 32 + df * 16 + (l & 15)) * 2048
                                         + m0 + ks * 32 + (l >> 4) * 8);
            accP[df] = __builtin_amdgcn_mfma_f32_16x16x32_bf16(pa, vb, accP[df], 0, 0, 0);
        }
    }
    #pragma unroll
    for (int df = 0; df < 2; df++)
        #pragma unroll
        for (int r = 0; r < 4; r++) {
            int gq = q0 + w * 16 + r4 + r;
            pvpart[((long long)S * 256 + gq) * 32 + df * 16 + (l & 15)] = accP[df][r];
        }
}

// ---------- 3. attn-out GEMM with inline combine (+ accept scan / cnt zero block) ----------
__global__ __launch_bounds__(256) void attn_gemm_k(
    const short* __restrict__ qkv_bf, const float* __restrict__ lpart,
    const float* __restrict__ pvpart,
    const short* __restrict__ outw_bf, float* __restrict__ attn_part,
    const float* __restrict__ sur, const int* __restrict__ ptr, int* __restrict__ inv,
    int* __restrict__ cnt)
{
    __shared__ float inv_n[64];
    __shared__ float es_n[64];
    __shared__ short Al[2560];
    __shared__ short Bl[2560];
    int j = blockIdx.x, t = threadIdx.x;
    if (j >= 128) {             // accept scan + ff2-LN counter zeroing
        __shared__ int ired[4];
        for (int m = t; m < 2048; m += 256) inv[m] = -1;
        if (t < 4) cnt[t] = 0;
        float s = sur[t];
        int p0 = ptr[0];
        int thresh = 2048 - p0;
        bool cond = (t < thresh) || (s > 0.5f);
        unsigned long long ball = __ballot(cond);
        int lane = t & 63, wv = t >> 6;
        if (lane == 0) ired[wv] = __popcll(ball);
        __syncthreads();
        int off = 0;
        for (int i = 0; i < wv; i++) off += ired[i];
        int rank = off + __popcll(ball & ((1ULL << lane) - 1ULL));
        if (cond) inv[(p0 + rank) & 2047] = t;
        return;
    }
    int h = j >> 4, r = j & 15, bx = r & 3, by = r >> 2;
    int b0 = by * 64, c0 = bx * 64;
    #pragma unroll
    for (int p = 0; p < 8; p++) {
        int rl = p * 8 + (t >> 5);
        int lane32 = t & 31;
        int b = b0 + rl;
        float q = frombf(qkv_bf[b * 768 + h * 32 + lane32]);
        float k = frombf(qkv_bf[b * 768 + 256 + h * 32 + lane32]);
        float prod = q * k;
        #pragma unroll
        for (int m = 16; m; m >>= 1) prod += __shfl_xor(prod, m, 64);
        float sl = prod * SCALE_F;
        if (lane32 < 8) {
            float lpv = lpart[(h * 8 + lane32) * 256 + b];
            #pragma unroll
            for (int m = 4; m; m >>= 1) lpv += __shfl_xor(lpv, m, 64);
            if (lane32 == 0) {
                float Es = __expf(sl);
                inv_n[rl] = 1.f / (lpv + Es);
                es_n[rl] = Es;
            }
        }
    }
    __syncthreads();
    {
        int rl = t >> 2, cg = (t & 3) * 8;
        int b = b0 + rl;
        short8 vs8 = *(const short8*)(qkv_bf + b * 768 + 512 + h * 32 + cg);
        float es = es_n[rl], iv = inv_n[rl];
        float a8[8];
        #pragma unroll
        for (int d = 0; d < 8; d++) a8[d] = es * frombf(vs8[d]);
        #pragma unroll
        for (int s = 0; s < 8; s++) {
            const float* pvb = pvpart + ((long long)(h * 8 + s) * 256 + b) * 32 + cg;
            float4 p0 = *(const float4*)pvb;
            float4 p1 = *(const float4*)(pvb + 4);
            a8[0] += p0.x; a8[1] += p0.y; a8[2] += p0.z; a8[3] += p0.w;
            a8[4] += p1.x; a8[5] += p1.y; a8[6] += p1.z; a8[7] += p1.w;
        }
        short8 o = {tobf(a8[0] * iv), tobf(a8[1] * iv), tobf(a8[2] * iv), tobf(a8[3] * iv),
                    tobf(a8[4] * iv), tobf(a8[5] * iv), tobf(a8[6] * iv), tobf(a8[7] * iv)};
        *(short8*)&Al[rl * 40 + cg] = o;
        *(short8*)&Bl[rl * 40 + cg] = *(const short8*)(outw_bf + (long long)(c0 + rl) * 256 + h * 32 + cg);
    }
    __syncthreads();
    int w = t >> 6, l = t & 63;
    short8 af = *(const short8*)&Al[(w * 16 + (l & 15)) * 40 + (l >> 4) * 8];
    f32x4 acc[4] = {{0.f,0.f,0.f,0.f},{0.f,0.f,0.f,0.f},{0.f,0.f,0.f,0.f},{0.f,0.f,0.f,0.f}};
    #pragma unroll
    for (int j4 = 0; j4 < 4; j4++) {
        short8 bf = *(const short8*)&Bl[(j4 * 16 + (l & 15)) * 40 + (l >> 4) * 8];
        acc[j4] = __builtin_amdgcn_mfma_f32_16x16x32_bf16(af, bf, acc[j4], 0, 0, 0);
    }
    int lc = l & 15, lr = (l >> 4) * 4;
    #pragma unroll
    for (int j4 = 0; j4 < 4; j4++) {
        int col = c0 + j4 * 16 + lc;
        #pragma unroll
        for (int rr = 0; rr < 4; rr++) {
            int row = b0 + w * 16 + lr + rr;
            attn_part[(long long)h * 65536 + row * 256 + col] = acc[j4][rr];
        }
    }
}

// ---------- 4. ff1 GEMM with inline LayerNorm A-staging ----------
__global__ __launch_bounds__(256) void ff1_ln_k(
    const float* __restrict__ attn_part, const float* __restrict__ out_b,
    const float* __restrict__ src, const float* __restrict__ g1,
    const float* __restrict__ be1, const short* __restrict__ w1_bf,
    const float* __restrict__ b1, float* __restrict__ hbuf, short* __restrict__ ff1_bf)
{
    __shared__ short Afull[32 * 264];
    __shared__ short Bl[2560];
    int bx = blockIdx.x, by = blockIdx.y;
    int t = threadIdx.x, w = t >> 6, l = t & 63;
    #pragma unroll
    for (int p = 0; p < 8; p++) {
        int rl = p * 4 + w;
        int r = by * 32 + rl;
        int c = l * 4;
        float4 x = *(const float4*)(out_b + c);
        float4 sv = *(const float4*)(src + (long long)r * 256 + c);
        x.x += sv.x; x.y += sv.y; x.z += sv.z; x.w += sv.w;
        #pragma unroll
        for (int pp = 0; pp < 8; pp++) {
            float4 a = *(const float4*)(attn_part + (long long)pp * 65536 + r * 256 + c);
            x.x += a.x; x.y += a.y; x.z += a.z; x.w += a.w;
        }
        float s = x.x + x.y + x.z + x.w;
        #pragma unroll
        for (int m = 32; m; m >>= 1) s += __shfl_xor(s, m, 64);
        float mean = s * (1.f / 256.f);
        float4 cv = {x.x - mean, x.y - mean, x.z - mean, x.w - mean};
        float ss = cv.x * cv.x + cv.y * cv.y + cv.z * cv.z + cv.w * cv.w;
        #pragma unroll
        for (int m = 32; m; m >>= 1) ss += __shfl_xor(ss, m, 64);
        float rstd = rsqrtf(ss * (1.f / 256.f) + 1e-5f);
        float4 gg = *(const float4*)(g1 + c);
        float4 bb = *(const float4*)(be1 + c);
        float4 y = {cv.x * rstd * gg.x + bb.x, cv.y * rstd * gg.y + bb.y,
                    cv.z * rstd * gg.z + bb.z, cv.w * rstd * gg.w + bb.w};
        if (bx == 0) *(float4*)(hbuf + (long long)r * 256 + c) = y;
        short4v yb = {tobf(y.x), tobf(y.y), tobf(y.z), tobf(y.w)};
        *(short4v*)&Afull[rl * 264 + c] = yb;
    }
    __syncthreads();
    int c0 = bx * 64;
    int srow = t >> 2, scol = (t & 3) * 8;
    int wr = w & 1, wc = w >> 1;
    f32x4 acc[2] = {{0.f,0.f,0.f,0.f},{0.f,0.f,0.f,0.f}};
    for (int kk = 0; kk < 256; kk += 32) {
        *(short8*)&Bl[srow * 40 + scol] = *(const short8*)(w1_bf + (long long)(c0 + srow) * 256 + kk + scol);
        __syncthreads();
        short8 af = *(const short8*)&Afull[(wr * 16 + (l & 15)) * 264 + kk + (l >> 4) * 8];
        #pragma unroll
        for (int jj = 0; jj < 2; jj++) {
            int j = wc * 2 + jj;
            short8 bf = *(const short8*)&Bl[(j * 16 + (l & 15)) * 40 + (l >> 4) * 8];
            acc[jj] = __builtin_amdgcn_mfma_f32_16x16x32_bf16(af, bf, acc[jj], 0, 0, 0);
        }
        __syncthreads();
    }
    int lc = l & 15, lr = (l >> 4) * 4;
    #pragma unroll
    for (int jj = 0; jj < 2; jj++) {
        int col = c0 + (wc * 2 + jj) * 16 + lc;
        float bv = b1[col];
        #pragma unroll
        for (int r = 0; r < 4; r++) {
            int row = by * 32 + wr * 16 + lr + r;
            float v = fmaxf(acc[jj][r] + bv, 0.f);
            ff1_bf[(long long)row * 1024 + col] = tobf(v);
        }
    }
}

// ---------- shared bf16 tile GEMM (k-split) for ff2 ----------
__device__ __forceinline__ void gemm_tile(short* lds,
    const short* __restrict__ A, int lda, const short* __restrict__ B, int ldb,
    float* Cf, int ldc, long long coff, int Klen, int kbeg, int bx, int by)
{
    short* Al = lds;
    short* Bl = lds + 2560;
    int t = threadIdx.x, w = t >> 6, l = t & 63;
    int r0 = by * 64, c0 = bx * 64;
    int srow = t >> 2, scol = (t & 3) * 8;
    f32x4 acc[4] = {{0.f,0.f,0.f,0.f},{0.f,0.f,0.f,0.f},{0.f,0.f,0.f,0.f},{0.f,0.f,0.f,0.f}};
    for (int kk = 0; kk < Klen; kk += 32) {
        int k0 = kbeg + kk;
        *(short8*)&Al[srow * 40 + scol] = *(const short8*)(A + (long long)(r0 + srow) * lda + k0 + scol);
        *(short8*)&Bl[srow * 40 + scol] = *(const short8*)(B + (long long)(c0 + srow) * ldb + k0 + scol);
        __syncthreads();
        short8 af = *(const short8*)&Al[(w * 16 + (l & 15)) * 40 + (l >> 4) * 8];
        #pragma unroll
        for (int j = 0; j < 4; j++) {
            short8 bf = *(const short8*)&Bl[(j * 16 + (l & 15)) * 40 + (l >> 4) * 8];
            acc[j] = __builtin_amdgcn_mfma_f32_16x16x32_bf16(af, bf, acc[j], 0, 0, 0);
        }
        __syncthreads();
    }
    int lc = l & 15, lr = (l >> 4) * 4;
    #pragma unroll
    for (int j = 0; j < 4; j++) {
        int col = c0 + j * 16 + lc;
        #pragma unroll
        for (int r = 0; r < 4; r++) {
            int row = r0 + w * 16 + lr + r;
            Cf[coff + (long long)row * ldc + col] = acc[j][r];
        }
    }
}

// ---------- 5. ff2 GEMM (k-split 8, fused final-LN via completion counter) || memupd ----------
__global__ __launch_bounds__(256) void ff2_mem_k(
    const short* __restrict__ ff1_bf, const short* __restrict__ w2_bf,
    float* __restrict__ ff2_part,
    const float* __restrict__ memory, const float* __restrict__ momentum,
    const float* __restrict__ scores, const float* __restrict__ hbuf,
    const float* __restrict__ sur, const int* __restrict__ inv,
    float* __restrict__ mem_o, float* __restrict__ mom_o, float* __restrict__ sc_o,
    const float* __restrict__ b2, const float* __restrict__ g2,
    const float* __restrict__ be2, float* __restrict__ out_main, int* __restrict__ cnt)
{
    __shared__ short lds[5120];
    __shared__ int s_old;
    int j = blockIdx.x, t = threadIdx.x;
    int w = t >> 6, l = t & 63;
    if (j < 128) {
        int ks = j >> 4, r = j & 15, bx = r & 3, by = r >> 2;
        gemm_tile(lds, ff1_bf, 1024, w2_bf, 1024, ff2_part, 256,
                  (long long)ks * 65536, 128, ks * 128, bx, by);
        __threadfence();                      // release partial writes
        if (t == 0) s_old = atomicAdd(&cnt[by], 1);
        __syncthreads();
        if (s_old == 31) {                    // last of 32 producers for this 64-row group
            __threadfence();                  // acquire others' writes
            #pragma unroll
            for (int i = 0; i < 16; i++) {
                int rr = by * 64 + w * 16 + i;
                int c = l * 4;
                float4 x = *(const float4*)(b2 + c);
                float4 hv = *(const float4*)(hbuf + (long long)rr * 256 + c);
                x.x += hv.x; x.y += hv.y; x.z += hv.z; x.w += hv.w;
                #pragma unroll
                for (int pp = 0; pp < 8; pp++) {
                    float4 a = *(const float4*)(ff2_part + (long long)pp * 65536 + rr * 256 + c);
                    x.x += a.x; x.y += a.y; x.z += a.z; x.w += a.w;
                }
                float s = x.x + x.y + x.z + x.w;
                #pragma unroll
                for (int m = 32; m; m >>= 1) s += __shfl_xor(s, m, 64);
                float mean = s * (1.f / 256.f);
                float4 cv = {x.x - mean, x.y - mean, x.z - mean, x.w - mean};
                float ss = cv.x * cv.x + cv.y * cv.y + cv.z * cv.z + cv.w * cv.w;
                #pragma unroll
                for (int m = 32; m; m >>= 1) ss += __shfl_xor(ss, m, 64);
                float rstd = rsqrtf(ss * (1.f / 256.f) + 1e-5f);
                float4 gg = *(const float4*)(g2 + c);
                float4 bb = *(const float4*)(be2 + c);
                float4 y = {cv.x * rstd * gg.x + bb.x, cv.y * rstd * gg.y + bb.y,
                            cv.z * rstd * gg.z + bb.z, cv.w * rstd * gg.w + bb.w};
                *(float4*)(out_main + (long long)rr * 256 + c) = y;
            }
        }
        return;
    }
    // memory update: 8 rows per block
    #pragma unroll
    for (int i = 0; i < 2; i++) {
        int m = (j - 128) * 8 + i * 4 + w;
        int b = inv[m];
        long long o = (long long)m * 256 + l * 4;
        float4 xm = *(const float4*)(memory + o);
        float4 mo = *(const float4*)(momentum + o);
        if (b >= 0) {
            float4 hb = *(const float4*)(hbuf + (long long)b * 256 + l * 4);
            float4 nmom = {0.9f * mo.x + 0.1f * (hb.x - xm.x), 0.9f * mo.y + 0.1f * (hb.y - xm.y),
                           0.9f * mo.z + 0.1f * (hb.z - xm.z), 0.9f * mo.w + 0.1f * (hb.w - xm.w)};
            float4 nm4 = {xm.x + 0.1f * nmom.x, xm.y + 0.1f * nmom.y,
                          xm.z + 0.1f * nmom.z, xm.w + 0.1f * nmom.w};
            *(float4*)(mem_o + o) = nm4;
            *(float4*)(mom_o + o) = nmom;
            if (l == 0) sc_o[m] = sur[b];
        } else {
            *(float4*)(mem_o + o) = xm;
            *(float4*)(mom_o + o) = mo;
            if (l == 0) sc_o[m] = scores[m];
        }
    }
}

extern "C" void kernel_launch(void* const* d_in, const int* in_sizes, int n_in,
                              void* d_out, int out_size, void* d_ws, size_t ws_size,
                              hipStream_t stream)
{
    const float* src      = (const float*)d_in[0];
    const float* memory   = (const float*)d_in[1];
    const float* momentum = (const float*)d_in[2];
    const float* scores   = (const float*)d_in[3];
    const float* ipw      = (const float*)d_in[4];
    const float* ipb      = (const float*)d_in[5];
    const float* out_w    = (const float*)d_in[6];
    const float* out_b    = (const float*)d_in[7];
    const float* w1       = (const float*)d_in[8];
    const float* b1       = (const float*)d_in[9];
    const float* w2       = (const float*)d_in[10];
    const float* b2       = (const float*)d_in[11];
    const float* g1       = (const float*)d_in[12];
    const float* be1      = (const float*)d_in[13];
    const float* g2       = (const float*)d_in[14];
    const float* be2      = (const float*)d_in[15];
    const int*   ptr      = (const int*)d_in[16];

    float* o = (float*)d_out;
    float* out_main = o;
    float* mem_o = o + 65536;
    float* mom_o = mem_o + 524288;
    float* sc_o  = mom_o + 524288;

    char* wp = (char*)d_ws;
    auto alloc = [&](size_t n) { void* q = (void*)wp; wp += (n + 255) & ~(size_t)255; return q; };
    short* qkv_bf   = (short*)alloc(393216);
    short* k_bf     = (short*)alloc(1048576);
    short* vt_bf    = (short*)alloc(1048576);
    short* outw_bf  = (short*)alloc(131072);
    short* w1_bf    = (short*)alloc(524288);
    short* w2_bf    = (short*)alloc(524288);
    short* ff1_bf   = (short*)alloc(524288);
    float* simdot   = (float*)alloc(2097152);
    float* pvpart   = (float*)alloc(2097152);
    float* lpart    = (float*)alloc(65536);
    float* attn_part= (float*)alloc(2097152);
    float* ff2_part = (float*)alloc(2097152);
    float* hbuf     = (float*)alloc(262144);
    float* nx       = (float*)alloc(1024);
    float* nm       = (float*)alloc(8192);
    float* nm2      = (float*)alloc(8192);
    float* sur      = (float*)alloc(1024);
    int*   inv      = (int*)alloc(8192);
    int*   cnt      = (int*)alloc(64);

    // 1. projections + conversions + norms
    proj_k<<<420, 256, 0, stream>>>(src, memory, ipw, ipb, out_w, w1, w2,
        simdot, qkv_bf, k_bf, vt_bf, outw_bf, w1_bf, w2_bf, nx, nm, nm2);
    // 2. flash attention || surprise
    flash_sur_k<<<512, 256, 0, stream>>>(qkv_bf, k_bf, vt_bf, pvpart, lpart,
        simdot, nx, nm, nm2, sur);
    // 3. attn-out GEMM (inline combine) + accept scan + cnt zero
    attn_gemm_k<<<129, 256, 0, stream>>>(qkv_bf, lpart, pvpart, outw_bf,
        attn_part, sur, ptr, inv, cnt);
    // 4. ff1 GEMM (inline LN1; bx==0 writes hbuf)
    ff1_ln_k<<<dim3(16, 8), 256, 0, stream>>>(attn_part, out_b, src, g1, be1,
        w1_bf, b1, hbuf, ff1_bf);
    // 5. ff2 GEMM (fused final LN) || memory update
    ff2_mem_k<<<384, 256, 0, stream>>>(ff1_bf, w2_bf, ff2_part,
        memory, momentum, scores, hbuf, sur, inv, mem_o, mom_o, sc_o,
        b2, g2, be2, out_main, cnt);
}

// Round 13
// 138.319 us; speedup vs baseline: 1.1759x; 1.1759x over previous
//
#include <hip/hip_runtime.h>
#include <hip/hip_bf16.h>
#include <math.h>

// B=256, D=256, H=8, FF=1024, M=2048
#define SCALE_F 0.17677669529663687f

typedef __attribute__((ext_vector_type(8))) short short8;
typedef __attribute__((ext_vector_type(4))) short short4v;
typedef __attribute__((ext_vector_type(4))) float f32x4;

__device__ inline short tobf(float x) {
    union { __hip_bfloat16 b; short s; } u;
    u.b = __float2bfloat16(x);
    return u.s;
}
__device__ inline float frombf(short s) {
    return __uint_as_float(((unsigned)(unsigned short)s) << 16);
}

__device__ __forceinline__ short8 cv8(const float* __restrict__ p) {
    float4 a = *(const float4*)p, b = *(const float4*)(p + 4);
    short8 o = {tobf(a.x), tobf(a.y), tobf(a.z), tobf(a.w),
                tobf(b.x), tobf(b.y), tobf(b.z), tobf(b.w)};
    return o;
}

// ---------- staged-convert GEMM 64x64 ----------
__device__ __forceinline__ void gemm_cv(short* lds,
    const float* __restrict__ A, int lda,
    const float* __restrict__ B, int ldb,
    short* Cb, int ldc, const float* bias, int bx, int by)
{
    short* Al = lds;
    short* Bl = lds + 2560;
    int t = threadIdx.x, w = t >> 6, l = t & 63;
    int r0 = by * 64, c0 = bx * 64;
    int srow = t >> 2, scol = (t & 3) * 8;
    f32x4 acc[4] = {{0.f,0.f,0.f,0.f},{0.f,0.f,0.f,0.f},{0.f,0.f,0.f,0.f},{0.f,0.f,0.f,0.f}};
    for (int kk = 0; kk < 256; kk += 32) {
        *(short8*)&Al[srow * 40 + scol] = cv8(A + (long long)(r0 + srow) * lda + kk + scol);
        *(short8*)&Bl[srow * 40 + scol] = cv8(B + (long long)(c0 + srow) * ldb + kk + scol);
        __syncthreads();
        short8 af = *(const short8*)&Al[(w * 16 + (l & 15)) * 40 + (l >> 4) * 8];
        #pragma unroll
        for (int j = 0; j < 4; j++) {
            short8 bf = *(const short8*)&Bl[(j * 16 + (l & 15)) * 40 + (l >> 4) * 8];
            acc[j] = __builtin_amdgcn_mfma_f32_16x16x32_bf16(af, bf, acc[j], 0, 0, 0);
        }
        __syncthreads();
    }
    int lc = l & 15, lr = (l >> 4) * 4;
    #pragma unroll
    for (int j = 0; j < 4; j++) {
        int col = c0 + j * 16 + lc;
        float bv = bias[col];
        #pragma unroll
        for (int r = 0; r < 4; r++) {
            int row = r0 + w * 16 + lr + r;
            Cb[(long long)row * ldc + col] = tobf(acc[j][r] + bv);
        }
    }
}

// ---------- staged-convert GEMM 64x128 (f32 out or dual k/vt) ----------
__device__ __forceinline__ void gemm_cv128(short* lds,
    const float* __restrict__ A, int lda,
    const float* __restrict__ B, int ldb,
    float* Cf, int ldcF, short* Ck, short* Cvt, const float* bias,
    int bx, int by)
{
    short* Al = lds;
    short* Bl = lds + 2560;
    int t = threadIdx.x, w = t >> 6, l = t & 63;
    int r0 = by * 64, c0 = bx * 128;
    int srow = t >> 2, scol = (t & 3) * 8;
    f32x4 acc[8] = {{0.f,0.f,0.f,0.f},{0.f,0.f,0.f,0.f},{0.f,0.f,0.f,0.f},{0.f,0.f,0.f,0.f},
                    {0.f,0.f,0.f,0.f},{0.f,0.f,0.f,0.f},{0.f,0.f,0.f,0.f},{0.f,0.f,0.f,0.f}};
    for (int kk = 0; kk < 256; kk += 32) {
        *(short8*)&Al[srow * 40 + scol] = cv8(A + (long long)(r0 + srow) * lda + kk + scol);
        #pragma unroll
        for (int s = 0; s < 2; s++) {
            int seg = t + s * 256;
            int brow = seg >> 2, boff = (seg & 3) * 8;
            *(short8*)&Bl[brow * 40 + boff] = cv8(B + (long long)(c0 + brow) * ldb + kk + boff);
        }
        __syncthreads();
        short8 af = *(const short8*)&Al[(w * 16 + (l & 15)) * 40 + (l >> 4) * 8];
        #pragma unroll
        for (int j = 0; j < 8; j++) {
            short8 bf = *(const short8*)&Bl[(j * 16 + (l & 15)) * 40 + (l >> 4) * 8];
            acc[j] = __builtin_amdgcn_mfma_f32_16x16x32_bf16(af, bf, acc[j], 0, 0, 0);
        }
        __syncthreads();
    }
    int lc = l & 15, lr = (l >> 4) * 4;
    #pragma unroll
    for (int j = 0; j < 8; j++) {
        int col = c0 + j * 16 + lc;
        float bv = bias ? bias[col] : 0.f;
        #pragma unroll
        for (int r = 0; r < 4; r++) {
            int row = r0 + w * 16 + lr + r;
            float v = acc[j][r] + bv;
            if (Cf) Cf[(long long)row * ldcF + col] = v;
            else if (col < 256) Ck[(long long)row * 256 + col] = tobf(v);
            else                Cvt[(long long)(col - 256) * 2048 + row] = tobf(v);
        }
    }
}

// ---------- 1. projections + conversions + norms (420 blocks) ----------
__global__ __launch_bounds__(256) void proj_k(
    const float* __restrict__ src, const float* __restrict__ memory,
    const float* __restrict__ ipw, const float* __restrict__ ipb,
    const float* __restrict__ out_w, const float* __restrict__ w1, const float* __restrict__ w2,
    float* __restrict__ simdot, short* __restrict__ qkv_bf,
    short* __restrict__ k_bf, short* __restrict__ vt_bf,
    short* __restrict__ outw_bf, short* __restrict__ w1_bf, short* __restrict__ w2_bf,
    float* __restrict__ nx, float* __restrict__ nm, float* __restrict__ nm2)
{
    __shared__ short lds[7680];
    int bid = blockIdx.x, t = threadIdx.x, w = t >> 6, l = t & 63;
    if (bid < 64) {
        gemm_cv128(lds, src, 256, memory, 256,
                   simdot, 2048, nullptr, nullptr, nullptr, bid & 15, bid >> 4);
    } else if (bid < 192) {
        int r = bid - 64;
        gemm_cv128(lds, memory, 256, ipw + 65536, 256,
                   nullptr, 0, k_bf, vt_bf, ipb + 256, r & 3, r >> 2);
    } else if (bid < 240) {
        int r = bid - 192;
        gemm_cv(lds, src, 256, ipw, 256, qkv_bf, 768, ipb, r % 12, r / 12);
    } else if (bid < 276) {
        int nb = bid - 240;
        #pragma unroll
        for (int i = 0; i < 16; i++) {
            int r = nb * 64 + i * 4 + w;
            bool issrc = r < 256;
            int rr = issrc ? r : r - 256;
            const float* rowp = issrc ? src + (long long)rr * 256 : memory + (long long)rr * 256;
            float4 x = *(const float4*)(rowp + l * 4);
            float ss = x.x * x.x + x.y * x.y + x.z * x.z + x.w * x.w;
            #pragma unroll
            for (int m = 32; m; m >>= 1) ss += __shfl_xor(ss, m, 64);
            if (l == 0) {
                if (issrc) nx[rr] = fmaxf(sqrtf(ss), 1e-8f);
                else { nm[rr] = fmaxf(sqrtf(ss), 1e-8f); nm2[rr] = ss; }
            }
        }
    } else {
        long long base = (long long)(bid - 276) * 4096 + t * 8;
        #pragma unroll
        for (int rep = 0; rep < 2; rep++) {
            long long e = base + rep * 2048;
            const float* sp; short* dp; long long off;
            if (e < 65536)       { sp = out_w; dp = outw_bf; off = e; }
            else if (e < 327680) { sp = w1;    dp = w1_bf;   off = e - 65536; }
            else                 { sp = w2;    dp = w2_bf;   off = e - 327680; }
            *(short8*)&dp[off] = cv8(sp + off);
        }
    }
}

// ---------- 2. flash attention (no-max softmax: logits bounded ~|0.6|) || surprise ----------
__global__ __launch_bounds__(256) void flash_sur_k(
    const short* __restrict__ qkv_bf, const short* __restrict__ k_bf,
    const short* __restrict__ vt_bf,
    float* __restrict__ pvpart, float* __restrict__ lpart,
    const float* __restrict__ simdot, const float* __restrict__ nx,
    const float* __restrict__ nm, const float* __restrict__ nm2, float* __restrict__ sur)
{
    __shared__ __align__(16) short smem[22016];   // Kl [128][40] | Pl [64][264]
    int bid = blockIdx.x, t = threadIdx.x;
    if (bid >= 256) {           // surprise
        float* red = (float*)smem;
        int b = bid - 256;
        float tot = 0.f;
        for (int m = t; m < 2048; m += 256) tot += nm2[m];
        red[t] = tot; __syncthreads();
        for (int s = 128; s; s >>= 1) { if (t < s) red[t] += red[t + s]; __syncthreads(); }
        float total = red[0];
        __syncthreads();
        float invx = 1.f / nx[b];
        float mx = -1e30f;
        for (int m = t; m < 2048; m += 256) {
            float d = simdot[(long long)b * 2048 + m];
            mx = fmaxf(mx, d * invx / nm[m]);
        }
        red[t] = mx; __syncthreads();
        for (int s = 128; s; s >>= 1) { if (t < s) red[t] = fmaxf(red[t], red[t + s]); __syncthreads(); }
        if (t == 0) sur[b] = (total == 0.f) ? 1.f : 1.f - red[0];
        return;
    }
    int ms = bid & 7, h = (bid >> 3) & 7, qt = bid >> 6;
    int q0 = qt * 64, m0 = ms * 256;
    int S = bid & 63;
    int w = t >> 6, l = t & 63;
    short* Kl = smem;
    short* Pl = smem + 5120;
    short8 af = *(const short8*)(qkv_bf + (q0 + w * 16 + (l & 15)) * 768 + h * 32 + (l >> 4) * 8);
    f32x4 accL[16];
    #pragma unroll
    for (int j = 0; j < 16; j++) accL[j] = f32x4{0.f, 0.f, 0.f, 0.f};
    #pragma unroll
    for (int half = 0; half < 2; half++) {
        #pragma unroll
        for (int s = 0; s < 2; s++) {
            int seg = t + s * 256; int row = seg >> 2, off = (seg & 3) * 8;
            *(short8*)&Kl[row * 40 + off] =
                *(const short8*)(k_bf + (long long)(m0 + half * 128 + row) * 256 + h * 32 + off);
        }
        __syncthreads();
        #pragma unroll
        for (int j = 0; j < 8; j++) {
            short8 bf = *(const short8*)&Kl[(j * 16 + (l & 15)) * 40 + (l >> 4) * 8];
            accL[half * 8 + j] = __builtin_amdgcn_mfma_f32_16x16x32_bf16(af, bf, accL[half * 8 + j], 0, 0, 0);
        }
        __syncthreads();
    }
    int r4 = (l >> 4) * 4;
    #pragma unroll
    for (int j = 0; j < 16; j++)
        #pragma unroll
        for (int r = 0; r < 4; r++)
            accL[j][r] = __expf(accL[j][r] * SCALE_F);
    float lsum[4];
    #pragma unroll
    for (int r = 0; r < 4; r++) {
        float ls = 0.f;
        #pragma unroll
        for (int j = 0; j < 16; j++) ls += accL[j][r];
        #pragma unroll
        for (int msk = 1; msk < 16; msk <<= 1) ls += __shfl_xor(ls, msk, 64);
        lsum[r] = ls;
    }
    if ((l & 15) == 0) {
        #pragma unroll
        for (int r = 0; r < 4; r++)
            lpart[S * 256 + q0 + w * 16 + r4 + r] = lsum[r];
    }
    #pragma unroll
    for (int j = 0; j < 16; j++)
        #pragma unroll
        for (int r = 0; r < 4; r++)
            Pl[(w * 16 + r4 + r) * 264 + j * 16 + (l & 15)] = tobf(accL[j][r]);
    __syncthreads();
    f32x4 accP[2] = {{0.f,0.f,0.f,0.f},{0.f,0.f,0.f,0.f}};
    #pragma unroll
    for (int ks = 0; ks < 8; ks++) {
        short8 pa = *(const short8*)&Pl[(w * 16 + (l & 15)) * 264 + ks * 32 + (l >> 4) * 8];
        #pragma unroll
        for (int df = 0; df < 2; df++) {
            short8 vb = *(const short8*)(vt_bf + (long long)(h * 32 + df * 16 + (l & 15)) * 2048
                                         + m0 + ks * 32 + (l >> 4) * 8);
            accP[df] = __builtin_amdgcn_mfma_f32_16x16x32_bf16(pa, vb, accP[df], 0, 0, 0);
        }
    }
    #pragma unroll
    for (int df = 0; df < 2; df++)
        #pragma unroll
        for (int r = 0; r < 4; r++) {
            int gq = q0 + w * 16 + r4 + r;
            pvpart[((long long)S * 256 + gq) * 32 + df * 16 + (l & 15)] = accP[df][r];
        }
}

// ---------- 3. attn-out GEMM with inline combine (+ accept scan block) ----------
__global__ __launch_bounds__(256) void attn_gemm_k(
    const short* __restrict__ qkv_bf, const float* __restrict__ lpart,
    const float* __restrict__ pvpart,
    const short* __restrict__ outw_bf, float* __restrict__ attn_part,
    const float* __restrict__ sur, const int* __restrict__ ptr, int* __restrict__ inv)
{
    __shared__ float inv_n[64];
    __shared__ float es_n[64];
    __shared__ short Al[2560];
    __shared__ short Bl[2560];
    int j = blockIdx.x, t = threadIdx.x;
    if (j >= 128) {             // accept scan (closed form + ballot prefix)
        __shared__ int ired[4];
        for (int m = t; m < 2048; m += 256) inv[m] = -1;
        float s = sur[t];
        int p0 = ptr[0];
        int thresh = 2048 - p0;
        bool cond = (t < thresh) || (s > 0.5f);
        unsigned long long ball = __ballot(cond);
        int lane = t & 63, wv = t >> 6;
        if (lane == 0) ired[wv] = __popcll(ball);
        __syncthreads();
        int off = 0;
        for (int i = 0; i < wv; i++) off += ired[i];
        int rank = off + __popcll(ball & ((1ULL << lane) - 1ULL));
        if (cond) inv[(p0 + rank) & 2047] = t;
        return;
    }
    int h = j >> 4, r = j & 15, bx = r & 3, by = r >> 2;
    int b0 = by * 64, c0 = bx * 64;
    #pragma unroll
    for (int p = 0; p < 8; p++) {
        int rl = p * 8 + (t >> 5);
        int lane32 = t & 31;
        int b = b0 + rl;
        float q = frombf(qkv_bf[b * 768 + h * 32 + lane32]);
        float k = frombf(qkv_bf[b * 768 + 256 + h * 32 + lane32]);
        float prod = q * k;
        #pragma unroll
        for (int m = 16; m; m >>= 1) prod += __shfl_xor(prod, m, 64);
        float sl = prod * SCALE_F;
        if (lane32 < 8) {
            float lpv = lpart[(h * 8 + lane32) * 256 + b];
            #pragma unroll
            for (int m = 4; m; m >>= 1) lpv += __shfl_xor(lpv, m, 64);
            if (lane32 == 0) {
                float Es = __expf(sl);
                inv_n[rl] = 1.f / (lpv + Es);
                es_n[rl] = Es;
            }
        }
    }
    __syncthreads();
    {
        int rl = t >> 2, cg = (t & 3) * 8;
        int b = b0 + rl;
        short8 vs8 = *(const short8*)(qkv_bf + b * 768 + 512 + h * 32 + cg);
        float es = es_n[rl], iv = inv_n[rl];
        float a8[8];
        #pragma unroll
        for (int d = 0; d < 8; d++) a8[d] = es * frombf(vs8[d]);
        #pragma unroll
        for (int s = 0; s < 8; s++) {
            const float* pvb = pvpart + ((long long)(h * 8 + s) * 256 + b) * 32 + cg;
            float4 p0 = *(const float4*)pvb;
            float4 p1 = *(const float4*)(pvb + 4);
            a8[0] += p0.x; a8[1] += p0.y; a8[2] += p0.z; a8[3] += p0.w;
            a8[4] += p1.x; a8[5] += p1.y; a8[6] += p1.z; a8[7] += p1.w;
        }
        short8 o = {tobf(a8[0] * iv), tobf(a8[1] * iv), tobf(a8[2] * iv), tobf(a8[3] * iv),
                    tobf(a8[4] * iv), tobf(a8[5] * iv), tobf(a8[6] * iv), tobf(a8[7] * iv)};
        *(short8*)&Al[rl * 40 + cg] = o;
        *(short8*)&Bl[rl * 40 + cg] = *(const short8*)(outw_bf + (long long)(c0 + rl) * 256 + h * 32 + cg);
    }
    __syncthreads();
    int w = t >> 6, l = t & 63;
    short8 af = *(const short8*)&Al[(w * 16 + (l & 15)) * 40 + (l >> 4) * 8];
    f32x4 acc[4] = {{0.f,0.f,0.f,0.f},{0.f,0.f,0.f,0.f},{0.f,0.f,0.f,0.f},{0.f,0.f,0.f,0.f}};
    #pragma unroll
    for (int j4 = 0; j4 < 4; j4++) {
        short8 bf = *(const short8*)&Bl[(j4 * 16 + (l & 15)) * 40 + (l >> 4) * 8];
        acc[j4] = __builtin_amdgcn_mfma_f32_16x16x32_bf16(af, bf, acc[j4], 0, 0, 0);
    }
    int lc = l & 15, lr = (l >> 4) * 4;
    #pragma unroll
    for (int j4 = 0; j4 < 4; j4++) {
        int col = c0 + j4 * 16 + lc;
        #pragma unroll
        for (int rr = 0; rr < 4; rr++) {
            int row = b0 + w * 16 + lr + rr;
            attn_part[(long long)h * 65536 + row * 256 + col] = acc[j4][rr];
        }
    }
}

// ---------- 4. ff1 GEMM with inline LayerNorm A-staging ----------
__global__ __launch_bounds__(256) void ff1_ln_k(
    const float* __restrict__ attn_part, const float* __restrict__ out_b,
    const float* __restrict__ src, const float* __restrict__ g1,
    const float* __restrict__ be1, const short* __restrict__ w1_bf,
    const float* __restrict__ b1, float* __restrict__ hbuf, short* __restrict__ ff1_bf)
{
    __shared__ short Afull[32 * 264];
    __shared__ short Bl[2560];
    int bx = blockIdx.x, by = blockIdx.y;
    int t = threadIdx.x, w = t >> 6, l = t & 63;
    #pragma unroll
    for (int p = 0; p < 8; p++) {
        int rl = p * 4 + w;
        int r = by * 32 + rl;
        int c = l * 4;
        float4 x = *(const float4*)(out_b + c);
        float4 sv = *(const float4*)(src + (long long)r * 256 + c);
        x.x += sv.x; x.y += sv.y; x.z += sv.z; x.w += sv.w;
        #pragma unroll
        for (int pp = 0; pp < 8; pp++) {
            float4 a = *(const float4*)(attn_part + (long long)pp * 65536 + r * 256 + c);
            x.x += a.x; x.y += a.y; x.z += a.z; x.w += a.w;
        }
        float s = x.x + x.y + x.z + x.w;
        #pragma unroll
        for (int m = 32; m; m >>= 1) s += __shfl_xor(s, m, 64);
        float mean = s * (1.f / 256.f);
        float4 cv = {x.x - mean, x.y - mean, x.z - mean, x.w - mean};
        float ss = cv.x * cv.x + cv.y * cv.y + cv.z * cv.z + cv.w * cv.w;
        #pragma unroll
        for (int m = 32; m; m >>= 1) ss += __shfl_xor(ss, m, 64);
        float rstd = rsqrtf(ss * (1.f / 256.f) + 1e-5f);
        float4 gg = *(const float4*)(g1 + c);
        float4 bb = *(const float4*)(be1 + c);
        float4 y = {cv.x * rstd * gg.x + bb.x, cv.y * rstd * gg.y + bb.y,
                    cv.z * rstd * gg.z + bb.z, cv.w * rstd * gg.w + bb.w};
        if (bx == 0) *(float4*)(hbuf + (long long)r * 256 + c) = y;
        short4v yb = {tobf(y.x), tobf(y.y), tobf(y.z), tobf(y.w)};
        *(short4v*)&Afull[rl * 264 + c] = yb;
    }
    __syncthreads();
    int c0 = bx * 64;
    int srow = t >> 2, scol = (t & 3) * 8;
    int wr = w & 1, wc = w >> 1;
    f32x4 acc[2] = {{0.f,0.f,0.f,0.f},{0.f,0.f,0.f,0.f}};
    for (int kk = 0; kk < 256; kk += 32) {
        *(short8*)&Bl[srow * 40 + scol] = *(const short8*)(w1_bf + (long long)(c0 + srow) * 256 + kk + scol);
        __syncthreads();
        short8 af = *(const short8*)&Afull[(wr * 16 + (l & 15)) * 264 + kk + (l >> 4) * 8];
        #pragma unroll
        for (int jj = 0; jj < 2; jj++) {
            int j = wc * 2 + jj;
            short8 bf = *(const short8*)&Bl[(j * 16 + (l & 15)) * 40 + (l >> 4) * 8];
            acc[jj] = __builtin_amdgcn_mfma_f32_16x16x32_bf16(af, bf, acc[jj], 0, 0, 0);
        }
        __syncthreads();
    }
    int lc = l & 15, lr = (l >> 4) * 4;
    #pragma unroll
    for (int jj = 0; jj < 2; jj++) {
        int col = c0 + (wc * 2 + jj) * 16 + lc;
        float bv = b1[col];
        #pragma unroll
        for (int r = 0; r < 4; r++) {
            int row = by * 32 + wr * 16 + lr + r;
            float v = fmaxf(acc[jj][r] + bv, 0.f);
            ff1_bf[(long long)row * 1024 + col] = tobf(v);
        }
    }
}

// ---------- shared bf16 tile GEMM (k-split) for ff2 ----------
__device__ __forceinline__ void gemm_tile(short* lds,
    const short* __restrict__ A, int lda, const short* __restrict__ B, int ldb,
    float* Cf, int ldc, long long coff, int Klen, int kbeg, int bx, int by)
{
    short* Al = lds;
    short* Bl = lds + 2560;
    int t = threadIdx.x, w = t >> 6, l = t & 63;
    int r0 = by * 64, c0 = bx * 64;
    int srow = t >> 2, scol = (t & 3) * 8;
    f32x4 acc[4] = {{0.f,0.f,0.f,0.f},{0.f,0.f,0.f,0.f},{0.f,0.f,0.f,0.f},{0.f,0.f,0.f,0.f}};
    for (int kk = 0; kk < Klen; kk += 32) {
        int k0 = kbeg + kk;
        *(short8*)&Al[srow * 40 + scol] = *(const short8*)(A + (long long)(r0 + srow) * lda + k0 + scol);
        *(short8*)&Bl[srow * 40 + scol] = *(const short8*)(B + (long long)(c0 + srow) * ldb + k0 + scol);
        __syncthreads();
        short8 af = *(const short8*)&Al[(w * 16 + (l & 15)) * 40 + (l >> 4) * 8];
        #pragma unroll
        for (int j = 0; j < 4; j++) {
            short8 bf = *(const short8*)&Bl[(j * 16 + (l & 15)) * 40 + (l >> 4) * 8];
            acc[j] = __builtin_amdgcn_mfma_f32_16x16x32_bf16(af, bf, acc[j], 0, 0, 0);
        }
        __syncthreads();
    }
    int lc = l & 15, lr = (l >> 4) * 4;
    #pragma unroll
    for (int j = 0; j < 4; j++) {
        int col = c0 + j * 16 + lc;
        #pragma unroll
        for (int r = 0; r < 4; r++) {
            int row = r0 + w * 16 + lr + r;
            Cf[coff + (long long)row * ldc + col] = acc[j][r];
        }
    }
}

// ---------- 5. ff2 GEMM (k-split 8) || memory update (8 rows/block) ----------
__global__ __launch_bounds__(256) void ff2_mem_k(
    const short* __restrict__ ff1_bf, const short* __restrict__ w2_bf,
    float* __restrict__ ff2_part,
    const float* __restrict__ memory, const float* __restrict__ momentum,
    const float* __restrict__ scores, const float* __restrict__ hbuf,
    const float* __restrict__ sur, const int* __restrict__ inv,
    float* __restrict__ mem_o, float* __restrict__ mom_o, float* __restrict__ sc_o)
{
    __shared__ short lds[5120];
    int j = blockIdx.x, t = threadIdx.x;
    int w = t >> 6, l = t & 63;
    if (j < 128) {
        int ks = j >> 4, r = j & 15;
        gemm_tile(lds, ff1_bf, 1024, w2_bf, 1024, ff2_part, 256,
                  (long long)ks * 65536, 128, ks * 128, r & 3, r >> 2);
        return;
    }
    #pragma unroll
    for (int i = 0; i < 2; i++) {
        int m = (j - 128) * 8 + i * 4 + w;
        int b = inv[m];
        long long o = (long long)m * 256 + l * 4;
        float4 xm = *(const float4*)(memory + o);
        float4 mo = *(const float4*)(momentum + o);
        if (b >= 0) {
            float4 hb = *(const float4*)(hbuf + (long long)b * 256 + l * 4);
            float4 nmom = {0.9f * mo.x + 0.1f * (hb.x - xm.x), 0.9f * mo.y + 0.1f * (hb.y - xm.y),
                           0.9f * mo.z + 0.1f * (hb.z - xm.z), 0.9f * mo.w + 0.1f * (hb.w - xm.w)};
            float4 nm4 = {xm.x + 0.1f * nmom.x, xm.y + 0.1f * nmom.y,
                          xm.z + 0.1f * nmom.z, xm.w + 0.1f * nmom.w};
            *(float4*)(mem_o + o) = nm4;
            *(float4*)(mom_o + o) = nmom;
            if (l == 0) sc_o[m] = sur[b];
        } else {
            *(float4*)(mem_o + o) = xm;
            *(float4*)(mom_o + o) = mo;
            if (l == 0) sc_o[m] = scores[m];
        }
    }
}

// ---------- 6. final LayerNorm ----------
__global__ __launch_bounds__(256) void ln2_k(
    const float* __restrict__ ff2_part, const float* __restrict__ b2,
    const float* __restrict__ hbuf, const float* __restrict__ g2,
    const float* __restrict__ be2, float* __restrict__ out_main)
{
    int t = threadIdx.x, w = t >> 6, l = t & 63;
    int r = blockIdx.x * 4 + w;
    int c = l * 4;
    float4 x = *(const float4*)(b2 + c);
    float4 hv = *(const float4*)(hbuf + (long long)r * 256 + c);
    x.x += hv.x; x.y += hv.y; x.z += hv.z; x.w += hv.w;
    #pragma unroll
    for (int pp = 0; pp < 8; pp++) {
        float4 a = *(const float4*)(ff2_part + (long long)pp * 65536 + r * 256 + c);
        x.x += a.x; x.y += a.y; x.z += a.z; x.w += a.w;
    }
    float s = x.x + x.y + x.z + x.w;
    #pragma unroll
    for (int m = 32; m; m >>= 1) s += __shfl_xor(s, m, 64);
    float mean = s * (1.f / 256.f);
    float4 cv = {x.x - mean, x.y - mean, x.z - mean, x.w - mean};
    float ss = cv.x * cv.x + cv.y * cv.y + cv.z * cv.z + cv.w * cv.w;
    #pragma unroll
    for (int m = 32; m; m >>= 1) ss += __shfl_xor(ss, m, 64);
    float rstd = rsqrtf(ss * (1.f / 256.f) + 1e-5f);
    float4 gg = *(const float4*)(g2 + c);
    float4 bb = *(const float4*)(be2 + c);
    float4 y = {cv.x * rstd * gg.x + bb.x, cv.y * rstd * gg.y + bb.y,
                cv.z * rstd * gg.z + bb.z, cv.w * rstd * gg.w + bb.w};
    *(float4*)(out_main + (long long)r * 256 + c) = y;
}

extern "C" void kernel_launch(void* const* d_in, const int* in_sizes, int n_in,
                              void* d_out, int out_size, void* d_ws, size_t ws_size,
                              hipStream_t stream)
{
    const float* src      = (const float*)d_in[0];
    const float* memory   = (const float*)d_in[1];
    const float* momentum = (const float*)d_in[2];
    const float* scores   = (const float*)d_in[3];
    const float* ipw      = (const float*)d_in[4];
    const float* ipb      = (const float*)d_in[5];
    const float* out_w    = (const float*)d_in[6];
    const float* out_b    = (const float*)d_in[7];
    const float* w1       = (const float*)d_in[8];
    const float* b1       = (const float*)d_in[9];
    const float* w2       = (const float*)d_in[10];
    const float* b2       = (const float*)d_in[11];
    const float* g1       = (const float*)d_in[12];
    const float* be1      = (const float*)d_in[13];
    const float* g2       = (const float*)d_in[14];
    const float* be2      = (const float*)d_in[15];
    const int*   ptr      = (const int*)d_in[16];

    float* o = (float*)d_out;
    float* out_main = o;
    float* mem_o = o + 65536;
    float* mom_o = mem_o + 524288;
    float* sc_o  = mom_o + 524288;

    char* wp = (char*)d_ws;
    auto alloc = [&](size_t n) { void* q = (void*)wp; wp += (n + 255) & ~(size_t)255; return q; };
    short* qkv_bf   = (short*)alloc(393216);
    short* k_bf     = (short*)alloc(1048576);
    short* vt_bf    = (short*)alloc(1048576);
    short* outw_bf  = (short*)alloc(131072);
    short* w1_bf    = (short*)alloc(524288);
    short* w2_bf    = (short*)alloc(524288);
    short* ff1_bf   = (short*)alloc(524288);
    float* simdot   = (float*)alloc(2097152);
    float* pvpart   = (float*)alloc(2097152);
    float* lpart    = (float*)alloc(65536);
    float* attn_part= (float*)alloc(2097152);
    float* ff2_part = (float*)alloc(2097152);
    float* hbuf     = (float*)alloc(262144);
    float* nx       = (float*)alloc(1024);
    float* nm       = (float*)alloc(8192);
    float* nm2      = (float*)alloc(8192);
    float* sur      = (float*)alloc(1024);
    int*   inv      = (int*)alloc(8192);

    // 1. projections + conversions + norms
    proj_k<<<420, 256, 0, stream>>>(src, memory, ipw, ipb, out_w, w1, w2,
        simdot, qkv_bf, k_bf, vt_bf, outw_bf, w1_bf, w2_bf, nx, nm, nm2);
    // 2. flash attention || surprise
    flash_sur_k<<<512, 256, 0, stream>>>(qkv_bf, k_bf, vt_bf, pvpart, lpart,
        simdot, nx, nm, nm2, sur);
    // 3. attn-out GEMM (inline combine) + accept scan
    attn_gemm_k<<<129, 256, 0, stream>>>(qkv_bf, lpart, pvpart, outw_bf,
        attn_part, sur, ptr, inv);
    // 4. ff1 GEMM (inline LN1; bx==0 writes hbuf)
    ff1_ln_k<<<dim3(16, 8), 256, 0, stream>>>(attn_part, out_b, src, g1, be1,
        w1_bf, b1, hbuf, ff1_bf);
    // 5. ff2 GEMM || memory update
    ff2_mem_k<<<384, 256, 0, stream>>>(ff1_bf, w2_bf, ff2_part,
        memory, momentum, scores, hbuf, sur, inv, mem_o, mom_o, sc_o);
    // 6. final LN
    ln2_k<<<64, 256, 0, stream>>>(ff2_part, b2, hbuf, g2, be2, out_main);
}

// Round 14
// 136.645 us; speedup vs baseline: 1.1903x; 1.0123x over previous
//
#include <hip/hip_runtime.h>
#include <hip/hip_bf16.h>
#include <math.h>

// B=256, D=256, H=8, FF=1024, M=2048
#define SCALE_F 0.17677669529663687f

typedef __attribute__((ext_vector_type(8))) short short8;
typedef __attribute__((ext_vector_type(4))) short short4v;
typedef __attribute__((ext_vector_type(4))) float f32x4;

__device__ inline short tobf(float x) {
    union { __hip_bfloat16 b; short s; } u;
    u.b = __float2bfloat16(x);
    return u.s;
}
__device__ inline float frombf(short s) {
    return __uint_as_float(((unsigned)(unsigned short)s) << 16);
}

__device__ __forceinline__ short8 cv8(const float* __restrict__ p) {
    float4 a = *(const float4*)p, b = *(const float4*)(p + 4);
    short8 o = {tobf(a.x), tobf(a.y), tobf(a.z), tobf(a.w),
                tobf(b.x), tobf(b.y), tobf(b.z), tobf(b.w)};
    return o;
}

// ---------- staged-convert GEMM 64x64 ----------
__device__ __forceinline__ void gemm_cv(short* lds,
    const float* __restrict__ A, int lda,
    const float* __restrict__ B, int ldb,
    short* Cb, int ldc, const float* bias, int bx, int by)
{
    short* Al = lds;
    short* Bl = lds + 2560;
    int t = threadIdx.x, w = t >> 6, l = t & 63;
    int r0 = by * 64, c0 = bx * 64;
    int srow = t >> 2, scol = (t & 3) * 8;
    f32x4 acc[4] = {{0.f,0.f,0.f,0.f},{0.f,0.f,0.f,0.f},{0.f,0.f,0.f,0.f},{0.f,0.f,0.f,0.f}};
    for (int kk = 0; kk < 256; kk += 32) {
        *(short8*)&Al[srow * 40 + scol] = cv8(A + (long long)(r0 + srow) * lda + kk + scol);
        *(short8*)&Bl[srow * 40 + scol] = cv8(B + (long long)(c0 + srow) * ldb + kk + scol);
        __syncthreads();
        short8 af = *(const short8*)&Al[(w * 16 + (l & 15)) * 40 + (l >> 4) * 8];
        #pragma unroll
        for (int j = 0; j < 4; j++) {
            short8 bf = *(const short8*)&Bl[(j * 16 + (l & 15)) * 40 + (l >> 4) * 8];
            acc[j] = __builtin_amdgcn_mfma_f32_16x16x32_bf16(af, bf, acc[j], 0, 0, 0);
        }
        __syncthreads();
    }
    int lc = l & 15, lr = (l >> 4) * 4;
    #pragma unroll
    for (int j = 0; j < 4; j++) {
        int col = c0 + j * 16 + lc;
        float bv = bias[col];
        #pragma unroll
        for (int r = 0; r < 4; r++) {
            int row = r0 + w * 16 + lr + r;
            Cb[(long long)row * ldc + col] = tobf(acc[j][r] + bv);
        }
    }
}

// ---------- staged-convert GEMM 64x128 (f32 out or dual k/vt) ----------
__device__ __forceinline__ void gemm_cv128(short* lds,
    const float* __restrict__ A, int lda,
    const float* __restrict__ B, int ldb,
    float* Cf, int ldcF, short* Ck, short* Cvt, const float* bias,
    int bx, int by)
{
    short* Al = lds;
    short* Bl = lds + 2560;
    int t = threadIdx.x, w = t >> 6, l = t & 63;
    int r0 = by * 64, c0 = bx * 128;
    int srow = t >> 2, scol = (t & 3) * 8;
    f32x4 acc[8] = {{0.f,0.f,0.f,0.f},{0.f,0.f,0.f,0.f},{0.f,0.f,0.f,0.f},{0.f,0.f,0.f,0.f},
                    {0.f,0.f,0.f,0.f},{0.f,0.f,0.f,0.f},{0.f,0.f,0.f,0.f},{0.f,0.f,0.f,0.f}};
    for (int kk = 0; kk < 256; kk += 32) {
        *(short8*)&Al[srow * 40 + scol] = cv8(A + (long long)(r0 + srow) * lda + kk + scol);
        #pragma unroll
        for (int s = 0; s < 2; s++) {
            int seg = t + s * 256;
            int brow = seg >> 2, boff = (seg & 3) * 8;
            *(short8*)&Bl[brow * 40 + boff] = cv8(B + (long long)(c0 + brow) * ldb + kk + boff);
        }
        __syncthreads();
        short8 af = *(const short8*)&Al[(w * 16 + (l & 15)) * 40 + (l >> 4) * 8];
        #pragma unroll
        for (int j = 0; j < 8; j++) {
            short8 bf = *(const short8*)&Bl[(j * 16 + (l & 15)) * 40 + (l >> 4) * 8];
            acc[j] = __builtin_amdgcn_mfma_f32_16x16x32_bf16(af, bf, acc[j], 0, 0, 0);
        }
        __syncthreads();
    }
    int lc = l & 15, lr = (l >> 4) * 4;
    #pragma unroll
    for (int j = 0; j < 8; j++) {
        int col = c0 + j * 16 + lc;
        float bv = bias ? bias[col] : 0.f;
        #pragma unroll
        for (int r = 0; r < 4; r++) {
            int row = r0 + w * 16 + lr + r;
            float v = acc[j][r] + bv;
            if (Cf) Cf[(long long)row * ldcF + col] = v;
            else if (col < 256) Ck[(long long)row * 256 + col] = tobf(v);
            else                Cvt[(long long)(col - 256) * 2048 + row] = tobf(v);
        }
    }
}

// ---------- 1. projections + conversions + norms (420 blocks) ----------
__global__ __launch_bounds__(256) void proj_k(
    const float* __restrict__ src, const float* __restrict__ memory,
    const float* __restrict__ ipw, const float* __restrict__ ipb,
    const float* __restrict__ out_w, const float* __restrict__ w1, const float* __restrict__ w2,
    float* __restrict__ simdot, short* __restrict__ qkv_bf,
    short* __restrict__ k_bf, short* __restrict__ vt_bf,
    short* __restrict__ outw_bf, short* __restrict__ w1_bf, short* __restrict__ w2_bf,
    float* __restrict__ nx, float* __restrict__ nm, float* __restrict__ nm2)
{
    __shared__ short lds[7680];
    int bid = blockIdx.x, t = threadIdx.x, w = t >> 6, l = t & 63;
    if (bid < 64) {
        gemm_cv128(lds, src, 256, memory, 256,
                   simdot, 2048, nullptr, nullptr, nullptr, bid & 15, bid >> 4);
    } else if (bid < 192) {
        int r = bid - 64;
        gemm_cv128(lds, memory, 256, ipw + 65536, 256,
                   nullptr, 0, k_bf, vt_bf, ipb + 256, r & 3, r >> 2);
    } else if (bid < 240) {
        int r = bid - 192;
        gemm_cv(lds, src, 256, ipw, 256, qkv_bf, 768, ipb, r % 12, r / 12);
    } else if (bid < 276) {
        int nb = bid - 240;
        #pragma unroll
        for (int i = 0; i < 16; i++) {
            int r = nb * 64 + i * 4 + w;
            bool issrc = r < 256;
            int rr = issrc ? r : r - 256;
            const float* rowp = issrc ? src + (long long)rr * 256 : memory + (long long)rr * 256;
            float4 x = *(const float4*)(rowp + l * 4);
            float ss = x.x * x.x + x.y * x.y + x.z * x.z + x.w * x.w;
            #pragma unroll
            for (int m = 32; m; m >>= 1) ss += __shfl_xor(ss, m, 64);
            if (l == 0) {
                if (issrc) nx[rr] = fmaxf(sqrtf(ss), 1e-8f);
                else { nm[rr] = fmaxf(sqrtf(ss), 1e-8f); nm2[rr] = ss; }
            }
        }
    } else {
        long long base = (long long)(bid - 276) * 4096 + t * 8;
        #pragma unroll
        for (int rep = 0; rep < 2; rep++) {
            long long e = base + rep * 2048;
            const float* sp; short* dp; long long off;
            if (e < 65536)       { sp = out_w; dp = outw_bf; off = e; }
            else if (e < 327680) { sp = w1;    dp = w1_bf;   off = e - 65536; }
            else                 { sp = w2;    dp = w2_bf;   off = e - 327680; }
            *(short8*)&dp[off] = cv8(sp + off);
        }
    }
}

// ---------- 2. flash attention v3: barrier-free, K/V direct from L2, Pl wave-local ----------
// LDS = Pl [64][264] only (33.8 KB -> 4 blocks/CU). Wave w owns Pl rows [w*16, w*16+16).
__global__ __launch_bounds__(256) void flash_sur_k(
    const short* __restrict__ qkv_bf, const short* __restrict__ k_bf,
    const short* __restrict__ vt_bf,
    float* __restrict__ pvpart, float* __restrict__ lpart,
    const float* __restrict__ simdot, const float* __restrict__ nx,
    const float* __restrict__ nm, const float* __restrict__ nm2, float* __restrict__ sur)
{
    __shared__ __align__(16) short smem[16896];   // Pl [64][264]
    int bid = blockIdx.x, t = threadIdx.x;
    if (bid >= 256) {           // surprise
        float* red = (float*)smem;
        int b = bid - 256;
        float tot = 0.f;
        for (int m = t; m < 2048; m += 256) tot += nm2[m];
        red[t] = tot; __syncthreads();
        for (int s = 128; s; s >>= 1) { if (t < s) red[t] += red[t + s]; __syncthreads(); }
        float total = red[0];
        __syncthreads();
        float invx = 1.f / nx[b];
        float mx = -1e30f;
        for (int m = t; m < 2048; m += 256) {
            float d = simdot[(long long)b * 2048 + m];
            mx = fmaxf(mx, d * invx / nm[m]);
        }
        red[t] = mx; __syncthreads();
        for (int s = 128; s; s >>= 1) { if (t < s) red[t] = fmaxf(red[t], red[t + s]); __syncthreads(); }
        if (t == 0) sur[b] = (total == 0.f) ? 1.f : 1.f - red[0];
        return;
    }
    int ms = bid & 7, h = (bid >> 3) & 7, qt = bid >> 6;
    int q0 = qt * 64, m0 = ms * 256;
    int S = bid & 63;
    int w = t >> 6, l = t & 63;
    short* Pl = smem;
    short8 af = *(const short8*)(qkv_bf + (q0 + w * 16 + (l & 15)) * 768 + h * 32 + (l >> 4) * 8);
    f32x4 accL[16];
    #pragma unroll
    for (int j = 0; j < 16; j++) accL[j] = f32x4{0.f, 0.f, 0.f, 0.f};
    // QK^T: K fragments straight from global (L2-hot), two halves of 8 to cap VGPRs
    #pragma unroll
    for (int half = 0; half < 2; half++) {
        #pragma unroll
        for (int j = 0; j < 8; j++) {
            int jj = half * 8 + j;
            short8 kf = *(const short8*)(k_bf
                + (long long)(m0 + jj * 16 + (l & 15)) * 256 + h * 32 + (l >> 4) * 8);
            accL[jj] = __builtin_amdgcn_mfma_f32_16x16x32_bf16(af, kf, accL[jj], 0, 0, 0);
        }
    }
    int r4 = (l >> 4) * 4;
    #pragma unroll
    for (int j = 0; j < 16; j++)
        #pragma unroll
        for (int r = 0; r < 4; r++)
            accL[j][r] = __expf(accL[j][r] * SCALE_F);
    float lsum[4];
    #pragma unroll
    for (int r = 0; r < 4; r++) {
        float ls = 0.f;
        #pragma unroll
        for (int j = 0; j < 16; j++) ls += accL[j][r];
        #pragma unroll
        for (int msk = 1; msk < 16; msk <<= 1) ls += __shfl_xor(ls, msk, 64);
        lsum[r] = ls;
    }
    if ((l & 15) == 0) {
        #pragma unroll
        for (int r = 0; r < 4; r++)
            lpart[S * 256 + q0 + w * 16 + r4 + r] = lsum[r];
    }
    // P -> wave-local LDS rows (no barrier: wave w writes & reads only rows w*16..+15)
    #pragma unroll
    for (int j = 0; j < 16; j++)
        #pragma unroll
        for (int r = 0; r < 4; r++)
            Pl[(w * 16 + r4 + r) * 264 + j * 16 + (l & 15)] = tobf(accL[j][r]);
    f32x4 accP[2] = {{0.f,0.f,0.f,0.f},{0.f,0.f,0.f,0.f}};
    #pragma unroll
    for (int ks = 0; ks < 8; ks++) {
        short8 pa = *(const short8*)&Pl[(w * 16 + (l & 15)) * 264 + ks * 32 + (l >> 4) * 8];
        #pragma unroll
        for (int df = 0; df < 2; df++) {
            short8 vb = *(const short8*)(vt_bf + (long long)(h * 32 + df * 16 + (l & 15)) * 2048
                                         + m0 + ks * 32 + (l >> 4) * 8);
            accP[df] = __builtin_amdgcn_mfma_f32_16x16x32_bf16(pa, vb, accP[df], 0, 0, 0);
        }
    }
    #pragma unroll
    for (int df = 0; df < 2; df++)
        #pragma unroll
        for (int r = 0; r < 4; r++) {
            int gq = q0 + w * 16 + r4 + r;
            pvpart[((long long)S * 256 + gq) * 32 + df * 16 + (l & 15)] = accP[df][r];
        }
}

// ---------- 3. attn-out GEMM with inline combine (+ accept scan block) ----------
__global__ __launch_bounds__(256) void attn_gemm_k(
    const short* __restrict__ qkv_bf, const float* __restrict__ lpart,
    const float* __restrict__ pvpart,
    const short* __restrict__ outw_bf, float* __restrict__ attn_part,
    const float* __restrict__ sur, const int* __restrict__ ptr, int* __restrict__ inv)
{
    __shared__ float inv_n[64];
    __shared__ float es_n[64];
    __shared__ short Al[2560];
    __shared__ short Bl[2560];
    int j = blockIdx.x, t = threadIdx.x;
    if (j >= 128) {             // accept scan (closed form + ballot prefix)
        __shared__ int ired[4];
        for (int m = t; m < 2048; m += 256) inv[m] = -1;
        float s = sur[t];
        int p0 = ptr[0];
        int thresh = 2048 - p0;
        bool cond = (t < thresh) || (s > 0.5f);
        unsigned long long ball = __ballot(cond);
        int lane = t & 63, wv = t >> 6;
        if (lane == 0) ired[wv] = __popcll(ball);
        __syncthreads();
        int off = 0;
        for (int i = 0; i < wv; i++) off += ired[i];
        int rank = off + __popcll(ball & ((1ULL << lane) - 1ULL));
        if (cond) inv[(p0 + rank) & 2047] = t;
        return;
    }
    int h = j >> 4, r = j & 15, bx = r & 3, by = r >> 2;
    int b0 = by * 64, c0 = bx * 64;
    #pragma unroll
    for (int p = 0; p < 8; p++) {
        int rl = p * 8 + (t >> 5);
        int lane32 = t & 31;
        int b = b0 + rl;
        float q = frombf(qkv_bf[b * 768 + h * 32 + lane32]);
        float k = frombf(qkv_bf[b * 768 + 256 + h * 32 + lane32]);
        float prod = q * k;
        #pragma unroll
        for (int m = 16; m; m >>= 1) prod += __shfl_xor(prod, m, 64);
        float sl = prod * SCALE_F;
        if (lane32 < 8) {
            float lpv = lpart[(h * 8 + lane32) * 256 + b];
            #pragma unroll
            for (int m = 4; m; m >>= 1) lpv += __shfl_xor(lpv, m, 64);
            if (lane32 == 0) {
                float Es = __expf(sl);
                inv_n[rl] = 1.f / (lpv + Es);
                es_n[rl] = Es;
            }
        }
    }
    __syncthreads();
    {
        int rl = t >> 2, cg = (t & 3) * 8;
        int b = b0 + rl;
        short8 vs8 = *(const short8*)(qkv_bf + b * 768 + 512 + h * 32 + cg);
        float es = es_n[rl], iv = inv_n[rl];
        float a8[8];
        #pragma unroll
        for (int d = 0; d < 8; d++) a8[d] = es * frombf(vs8[d]);
        #pragma unroll
        for (int s = 0; s < 8; s++) {
            const float* pvb = pvpart + ((long long)(h * 8 + s) * 256 + b) * 32 + cg;
            float4 p0 = *(const float4*)pvb;
            float4 p1 = *(const float4*)(pvb + 4);
            a8[0] += p0.x; a8[1] += p0.y; a8[2] += p0.z; a8[3] += p0.w;
            a8[4] += p1.x; a8[5] += p1.y; a8[6] += p1.z; a8[7] += p1.w;
        }
        short8 o = {tobf(a8[0] * iv), tobf(a8[1] * iv), tobf(a8[2] * iv), tobf(a8[3] * iv),
                    tobf(a8[4] * iv), tobf(a8[5] * iv), tobf(a8[6] * iv), tobf(a8[7] * iv)};
        *(short8*)&Al[rl * 40 + cg] = o;
        *(short8*)&Bl[rl * 40 + cg] = *(const short8*)(outw_bf + (long long)(c0 + rl) * 256 + h * 32 + cg);
    }
    __syncthreads();
    int w = t >> 6, l = t & 63;
    short8 af = *(const short8*)&Al[(w * 16 + (l & 15)) * 40 + (l >> 4) * 8];
    f32x4 acc[4] = {{0.f,0.f,0.f,0.f},{0.f,0.f,0.f,0.f},{0.f,0.f,0.f,0.f},{0.f,0.f,0.f,0.f}};
    #pragma unroll
    for (int j4 = 0; j4 < 4; j4++) {
        short8 bf = *(const short8*)&Bl[(j4 * 16 + (l & 15)) * 40 + (l >> 4) * 8];
        acc[j4] = __builtin_amdgcn_mfma_f32_16x16x32_bf16(af, bf, acc[j4], 0, 0, 0);
    }
    int lc = l & 15, lr = (l >> 4) * 4;
    #pragma unroll
    for (int j4 = 0; j4 < 4; j4++) {
        int col = c0 + j4 * 16 + lc;
        #pragma unroll
        for (int rr = 0; rr < 4; rr++) {
            int row = b0 + w * 16 + lr + rr;
            attn_part[(long long)h * 65536 + row * 256 + col] = acc[j4][rr];
        }
    }
}

// ---------- 4. ff1 GEMM with inline LayerNorm A-staging ----------
__global__ __launch_bounds__(256) void ff1_ln_k(
    const float* __restrict__ attn_part, const float* __restrict__ out_b,
    const float* __restrict__ src, const float* __restrict__ g1,
    const float* __restrict__ be1, const short* __restrict__ w1_bf,
    const float* __restrict__ b1, float* __restrict__ hbuf, short* __restrict__ ff1_bf)
{
    __shared__ short Afull[32 * 264];
    __shared__ short Bl[2560];
    int bx = blockIdx.x, by = blockIdx.y;
    int t = threadIdx.x, w = t >> 6, l = t & 63;
    #pragma unroll
    for (int p = 0; p < 8; p++) {
        int rl = p * 4 + w;
        int r = by * 32 + rl;
        int c = l * 4;
        float4 x = *(const float4*)(out_b + c);
        float4 sv = *(const float4*)(src + (long long)r * 256 + c);
        x.x += sv.x; x.y += sv.y; x.z += sv.z; x.w += sv.w;
        #pragma unroll
        for (int pp = 0; pp < 8; pp++) {
            float4 a = *(const float4*)(attn_part + (long long)pp * 65536 + r * 256 + c);
            x.x += a.x; x.y += a.y; x.z += a.z; x.w += a.w;
        }
        float s = x.x + x.y + x.z + x.w;
        #pragma unroll
        for (int m = 32; m; m >>= 1) s += __shfl_xor(s, m, 64);
        float mean = s * (1.f / 256.f);
        float4 cv = {x.x - mean, x.y - mean, x.z - mean, x.w - mean};
        float ss = cv.x * cv.x + cv.y * cv.y + cv.z * cv.z + cv.w * cv.w;
        #pragma unroll
        for (int m = 32; m; m >>= 1) ss += __shfl_xor(ss, m, 64);
        float rstd = rsqrtf(ss * (1.f / 256.f) + 1e-5f);
        float4 gg = *(const float4*)(g1 + c);
        float4 bb = *(const float4*)(be1 + c);
        float4 y = {cv.x * rstd * gg.x + bb.x, cv.y * rstd * gg.y + bb.y,
                    cv.z * rstd * gg.z + bb.z, cv.w * rstd * gg.w + bb.w};
        if (bx == 0) *(float4*)(hbuf + (long long)r * 256 + c) = y;
        short4v yb = {tobf(y.x), tobf(y.y), tobf(y.z), tobf(y.w)};
        *(short4v*)&Afull[rl * 264 + c] = yb;
    }
    __syncthreads();
    int c0 = bx * 64;
    int srow = t >> 2, scol = (t & 3) * 8;
    int wr = w & 1, wc = w >> 1;
    f32x4 acc[2] = {{0.f,0.f,0.f,0.f},{0.f,0.f,0.f,0.f}};
    for (int kk = 0; kk < 256; kk += 32) {
        *(short8*)&Bl[srow * 40 + scol] = *(const short8*)(w1_bf + (long long)(c0 + srow) * 256 + kk + scol);
        __syncthreads();
        short8 af = *(const short8*)&Afull[(wr * 16 + (l & 15)) * 264 + kk + (l >> 4) * 8];
        #pragma unroll
        for (int jj = 0; jj < 2; jj++) {
            int j = wc * 2 + jj;
            short8 bf = *(const short8*)&Bl[(j * 16 + (l & 15)) * 40 + (l >> 4) * 8];
            acc[jj] = __builtin_amdgcn_mfma_f32_16x16x32_bf16(af, bf, acc[jj], 0, 0, 0);
        }
        __syncthreads();
    }
    int lc = l & 15, lr = (l >> 4) * 4;
    #pragma unroll
    for (int jj = 0; jj < 2; jj++) {
        int col = c0 + (wc * 2 + jj) * 16 + lc;
        float bv = b1[col];
        #pragma unroll
        for (int r = 0; r < 4; r++) {
            int row = by * 32 + wr * 16 + lr + r;
            float v = fmaxf(acc[jj][r] + bv, 0.f);
            ff1_bf[(long long)row * 1024 + col] = tobf(v);
        }
    }
}

// ---------- shared bf16 tile GEMM (k-split) for ff2 ----------
__device__ __forceinline__ void gemm_tile(short* lds,
    const short* __restrict__ A, int lda, const short* __restrict__ B, int ldb,
    float* Cf, int ldc, long long coff, int Klen, int kbeg, int bx, int by)
{
    short* Al = lds;
    short* Bl = lds + 2560;
    int t = threadIdx.x, w = t >> 6, l = t & 63;
    int r0 = by * 64, c0 = bx * 64;
    int srow = t >> 2, scol = (t & 3) * 8;
    f32x4 acc[4] = {{0.f,0.f,0.f,0.f},{0.f,0.f,0.f,0.f},{0.f,0.f,0.f,0.f},{0.f,0.f,0.f,0.f}};
    for (int kk = 0; kk < Klen; kk += 32) {
        int k0 = kbeg + kk;
        *(short8*)&Al[srow * 40 + scol] = *(const short8*)(A + (long long)(r0 + srow) * lda + k0 + scol);
        *(short8*)&Bl[srow * 40 + scol] = *(const short8*)(B + (long long)(c0 + srow) * ldb + k0 + scol);
        __syncthreads();
        short8 af = *(const short8*)&Al[(w * 16 + (l & 15)) * 40 + (l >> 4) * 8];
        #pragma unroll
        for (int j = 0; j < 4; j++) {
            short8 bf = *(const short8*)&Bl[(j * 16 + (l & 15)) * 40 + (l >> 4) * 8];
            acc[j] = __builtin_amdgcn_mfma_f32_16x16x32_bf16(af, bf, acc[j], 0, 0, 0);
        }
        __syncthreads();
    }
    int lc = l & 15, lr = (l >> 4) * 4;
    #pragma unroll
    for (int j = 0; j < 4; j++) {
        int col = c0 + j * 16 + lc;
        #pragma unroll
        for (int r = 0; r < 4; r++) {
            int row = r0 + w * 16 + lr + r;
            Cf[coff + (long long)row * ldc + col] = acc[j][r];
        }
    }
}

// ---------- 5. ff2 GEMM (k-split 8) || memory update (8 rows/block) ----------
__global__ __launch_bounds__(256) void ff2_mem_k(
    const short* __restrict__ ff1_bf, const short* __restrict__ w2_bf,
    float* __restrict__ ff2_part,
    const float* __restrict__ memory, const float* __restrict__ momentum,
    const float* __restrict__ scores, const float* __restrict__ hbuf,
    const float* __restrict__ sur, const int* __restrict__ inv,
    float* __restrict__ mem_o, float* __restrict__ mom_o, float* __restrict__ sc_o)
{
    __shared__ short lds[5120];
    int j = blockIdx.x, t = threadIdx.x;
    int w = t >> 6, l = t & 63;
    if (j < 128) {
        int ks = j >> 4, r = j & 15;
        gemm_tile(lds, ff1_bf, 1024, w2_bf, 1024, ff2_part, 256,
                  (long long)ks * 65536, 128, ks * 128, r & 3, r >> 2);
        return;
    }
    #pragma unroll
    for (int i = 0; i < 2; i++) {
        int m = (j - 128) * 8 + i * 4 + w;
        int b = inv[m];
        long long o = (long long)m * 256 + l * 4;
        float4 xm = *(const float4*)(memory + o);
        float4 mo = *(const float4*)(momentum + o);
        if (b >= 0) {
            float4 hb = *(const float4*)(hbuf + (long long)b * 256 + l * 4);
            float4 nmom = {0.9f * mo.x + 0.1f * (hb.x - xm.x), 0.9f * mo.y + 0.1f * (hb.y - xm.y),
                           0.9f * mo.z + 0.1f * (hb.z - xm.z), 0.9f * mo.w + 0.1f * (hb.w - xm.w)};
            float4 nm4 = {xm.x + 0.1f * nmom.x, xm.y + 0.1f * nmom.y,
                          xm.z + 0.1f * nmom.z, xm.w + 0.1f * nmom.w};
            *(float4*)(mem_o + o) = nm4;
            *(float4*)(mom_o + o) = nmom;
            if (l == 0) sc_o[m] = sur[b];
        } else {
            *(float4*)(mem_o + o) = xm;
            *(float4*)(mom_o + o) = mo;
            if (l == 0) sc_o[m] = scores[m];
        }
    }
}

// ---------- 6. final LayerNorm ----------
__global__ __launch_bounds__(256) void ln2_k(
    const float* __restrict__ ff2_part, const float* __restrict__ b2,
    const float* __restrict__ hbuf, const float* __restrict__ g2,
    const float* __restrict__ be2, float* __restrict__ out_main)
{
    int t = threadIdx.x, w = t >> 6, l = t & 63;
    int r = blockIdx.x * 4 + w;
    int c = l * 4;
    float4 x = *(const float4*)(b2 + c);
    float4 hv = *(const float4*)(hbuf + (long long)r * 256 + c);
    x.x += hv.x; x.y += hv.y; x.z += hv.z; x.w += hv.w;
    #pragma unroll
    for (int pp = 0; pp < 8; pp++) {
        float4 a = *(const float4*)(ff2_part + (long long)pp * 65536 + r * 256 + c);
        x.x += a.x; x.y += a.y; x.z += a.z; x.w += a.w;
    }
    float s = x.x + x.y + x.z + x.w;
    #pragma unroll
    for (int m = 32; m; m >>= 1) s += __shfl_xor(s, m, 64);
    float mean = s * (1.f / 256.f);
    float4 cv = {x.x - mean, x.y - mean, x.z - mean, x.w - mean};
    float ss = cv.x * cv.x + cv.y * cv.y + cv.z * cv.z + cv.w * cv.w;
    #pragma unroll
    for (int m = 32; m; m >>= 1) ss += __shfl_xor(ss, m, 64);
    float rstd = rsqrtf(ss * (1.f / 256.f) + 1e-5f);
    float4 gg = *(const float4*)(g2 + c);
    float4 bb = *(const float4*)(be2 + c);
    float4 y = {cv.x * rstd * gg.x + bb.x, cv.y * rstd * gg.y + bb.y,
                cv.z * rstd * gg.z + bb.z, cv.w * rstd * gg.w + bb.w};
    *(float4*)(out_main + (long long)r * 256 + c) = y;
}

extern "C" void kernel_launch(void* const* d_in, const int* in_sizes, int n_in,
                              void* d_out, int out_size, void* d_ws, size_t ws_size,
                              hipStream_t stream)
{
    const float* src      = (const float*)d_in[0];
    const float* memory   = (const float*)d_in[1];
    const float* momentum = (const float*)d_in[2];
    const float* scores   = (const float*)d_in[3];
    const float* ipw      = (const float*)d_in[4];
    const float* ipb      = (const float*)d_in[5];
    const float* out_w    = (const float*)d_in[6];
    const float* out_b    = (const float*)d_in[7];
    const float* w1       = (const float*)d_in[8];
    const float* b1       = (const float*)d_in[9];
    const float* w2       = (const float*)d_in[10];
    const float* b2       = (const float*)d_in[11];
    const float* g1       = (const float*)d_in[12];
    const float* be1      = (const float*)d_in[13];
    const float* g2       = (const float*)d_in[14];
    const float* be2      = (const float*)d_in[15];
    const int*   ptr      = (const int*)d_in[16];

    float* o = (float*)d_out;
    float* out_main = o;
    float* mem_o = o + 65536;
    float* mom_o = mem_o + 524288;
    float* sc_o  = mom_o + 524288;

    char* wp = (char*)d_ws;
    auto alloc = [&](size_t n) { void* q = (void*)wp; wp += (n + 255) & ~(size_t)255; return q; };
    short* qkv_bf   = (short*)alloc(393216);
    short* k_bf     = (short*)alloc(1048576);
    short* vt_bf    = (short*)alloc(1048576);
    short* outw_bf  = (short*)alloc(131072);
    short* w1_bf    = (short*)alloc(524288);
    short* w2_bf    = (short*)alloc(524288);
    short* ff1_bf   = (short*)alloc(524288);
    float* simdot   = (float*)alloc(2097152);
    float* pvpart   = (float*)alloc(2097152);
    float* lpart    = (float*)alloc(65536);
    float* attn_part= (float*)alloc(2097152);
    float* ff2_part = (float*)alloc(2097152);
    float* hbuf     = (float*)alloc(262144);
    float* nx       = (float*)alloc(1024);
    float* nm       = (float*)alloc(8192);
    float* nm2      = (float*)alloc(8192);
    float* sur      = (float*)alloc(1024);
    int*   inv      = (int*)alloc(8192);

    // 1. projections + conversions + norms
    proj_k<<<420, 256, 0, stream>>>(src, memory, ipw, ipb, out_w, w1, w2,
        simdot, qkv_bf, k_bf, vt_bf, outw_bf, w1_bf, w2_bf, nx, nm, nm2);
    // 2. flash attention (barrier-free) || surprise
    flash_sur_k<<<512, 256, 0, stream>>>(qkv_bf, k_bf, vt_bf, pvpart, lpart,
        simdot, nx, nm, nm2, sur);
    // 3. attn-out GEMM (inline combine) + accept scan
    attn_gemm_k<<<129, 256, 0, stream>>>(qkv_bf, lpart, pvpart, outw_bf,
        attn_part, sur, ptr, inv);
    // 4. ff1 GEMM (inline LN1; bx==0 writes hbuf)
    ff1_ln_k<<<dim3(16, 8), 256, 0, stream>>>(attn_part, out_b, src, g1, be1,
        w1_bf, b1, hbuf, ff1_bf);
    // 5. ff2 GEMM || memory update
    ff2_mem_k<<<384, 256, 0, stream>>>(ff1_bf, w2_bf, ff2_part,
        memory, momentum, scores, hbuf, sur, inv, mem_o, mom_o, sc_o);
    // 6. final LN
    ln2_k<<<64, 256, 0, stream>>>(ff2_part, b2, hbuf, g2, be2, out_main);
}